// Round 4
// baseline (539.515 us; speedup 1.0000x reference)
//
#include <hip/hip_runtime.h>

// ============================= DIAGNOSTIC ROUND =============================
// Cosine similarity per row (q,d: [N,256] fp32; out: [N] fp32), R1 structure,
// PLUS one dead re-read pass over XOR-permuted rows so the kernel's duration
// doubles and it surfaces in the rocprof top-5 (cut ~159us). Purpose: obtain
// the kernel's OWN counters (dur, hbm_gbps, FETCH_SIZE, VALUBusy, Occupancy)
// for the first time -- 3 rounds of structural changes were all neutral and
// the kernel has only ever been inferred, never measured.
//   T1 (true single-pass time) = dur(kernel)/2.
//   If T1 <= ~95us -> kernel at HBM floor, residual is harness -> ROOFLINE.
//   If T1 ~140us   -> kernel caps at ~3.7 TB/s; counters say why.
// Output is BIT-EXACT identical to R1: pass-2 loads feed only an empty
// asm volatile liveness sink (rule #17), never the result.
// ===========================================================================
typedef float fx4 __attribute__((ext_vector_type(4)));

constexpr int ROWS_PER_WAVE = 4;   // 16 lanes per row, 4 rows per wave
constexpr int WAVES_PER_BLOCK = 4; // 256 threads

__global__ __launch_bounds__(256) void cosine_rows_kernel(
    const fx4* __restrict__ q4,   // [N, 64] fx4 view of [N,256] f32
    const fx4* __restrict__ d4,
    float* __restrict__ out,      // [N] f32
    int n_rows)
{
    const int wave = (blockIdx.x * blockDim.x + threadIdx.x) >> 6;
    const int lane = threadIdx.x & 63;
    const int g    = lane >> 4;    // which of the wave's 4 rows
    const int c    = lane & 15;    // chunk lane within the row
    const int row  = wave * ROWS_PER_WAVE + g;
    if (row >= n_rows) return;

    const size_t base = (size_t)row * 64 + c;

    // --- real pass (identical to R1) ---
    fx4 qv[4], dv[4];
    #pragma unroll
    for (int k = 0; k < 4; ++k)
        qv[k] = __builtin_nontemporal_load(&q4[base + 16 * k]);
    #pragma unroll
    for (int k = 0; k < 4; ++k)
        dv[k] = __builtin_nontemporal_load(&d4[base + 16 * k]);

    // --- diagnostic pass: same footprint, XOR-permuted rows (bijection,
    // disjoint from this wave's real rows, so no CSE), nt loads ---
    int rowx = row ^ 64;
    if (rowx >= n_rows) rowx = row;          // safety for odd N (not hit here)
    const size_t basex = (size_t)rowx * 64 + c;
    fx4 xq[4], xd[4];
    #pragma unroll
    for (int k = 0; k < 4; ++k)
        xq[k] = __builtin_nontemporal_load(&q4[basex + 16 * k]);
    #pragma unroll
    for (int k = 0; k < 4; ++k)
        xd[k] = __builtin_nontemporal_load(&d4[basex + 16 * k]);

    // --- compute (pass-1 data only; bit-exact vs R1) ---
    float qq = 0.0f, dd = 0.0f, qd = 0.0f;
    #pragma unroll
    for (int k = 0; k < 4; ++k) {
        qq += qv[k].x * qv[k].x + qv[k].y * qv[k].y +
              qv[k].z * qv[k].z + qv[k].w * qv[k].w;
        dd += dv[k].x * dv[k].x + dv[k].y * dv[k].y +
              dv[k].z * dv[k].z + dv[k].w * dv[k].w;
        qd += qv[k].x * dv[k].x + qv[k].y * dv[k].y +
              qv[k].z * dv[k].z + qv[k].w * dv[k].w;
    }

    #pragma unroll
    for (int off = 8; off > 0; off >>= 1) {
        qq += __shfl_xor(qq, off, 64);
        dd += __shfl_xor(dd, off, 64);
        qd += __shfl_xor(qd, off, 64);
    }

    // Liveness sinks for the diagnostic pass: zero instructions, but the
    // loads must complete and cannot be dead-code-eliminated (rule #17).
    #pragma unroll
    for (int k = 0; k < 4; ++k) {
        asm volatile("" :: "v"(xq[k].x), "v"(xq[k].y), "v"(xq[k].z), "v"(xq[k].w));
        asm volatile("" :: "v"(xd[k].x), "v"(xd[k].y), "v"(xd[k].z), "v"(xd[k].w));
    }

    if (c == 0) {
        __builtin_nontemporal_store(qd * rsqrtf(qq * dd), &out[row]);
    }
}

extern "C" void kernel_launch(void* const* d_in, const int* in_sizes, int n_in,
                              void* d_out, int out_size, void* d_ws, size_t ws_size,
                              hipStream_t stream) {
    const fx4* q4 = (const fx4*)d_in[0];
    const fx4* d4 = (const fx4*)d_in[1];
    float* out = (float*)d_out;

    const int D = 256;
    const int n_rows = in_sizes[0] / D;   // 262144

    const int rows_per_block = WAVES_PER_BLOCK * ROWS_PER_WAVE;  // 16
    const int grid = (n_rows + rows_per_block - 1) / rows_per_block;

    cosine_rows_kernel<<<grid, 256, 0, stream>>>(q4, d4, out, n_rows);
}

// Round 6
// 497.102 us; speedup vs baseline: 1.0853x; 1.0853x over previous
//
#include <hip/hip_runtime.h>
#include <stdint.h>

// Cosine similarity per row: q,d are [N, 256] fp32; out is [N] fp32.
//
// R6 = R5 retried (run died on container infra failure, no data).
// Experiment: global_load_lds (direct global->LDS DMA) instead of
// VGPR-return loads. R4's counters excluded every software limiter
// (occupancy 77%, VALUBusy 7.7%, 0 bank conflicts, FETCH_SIZE == exact
// 537 MB footprint) yet VGPR-return reads cap at 3.35-3.7 TB/s across
// three concurrency structures -> suspected TCP/MSHR outstanding-line
// limit on the read-return path. global_load_lds is the one read path
// with different request tracking. Fills prove 6.7 TB/s pure-write on
// the same memory.
//
// Structure: each wave stages its OWN 4 q-rows + 4 d-rows (8 KiB) into a
// wave-private LDS slice, one 1-KiB row per DMA instruction (LDS dest is
// wave-uniform base + lane*16 B per m104/m173; global src is per-lane).
// Then s_waitcnt vmcnt(0) (+ sched_barrier per rule #18) and reduce from
// the private slice. No __syncthreads anywhere -> no barrier-drain stall,
// no cross-wave hazards. 32 KiB LDS/block.
typedef float fx4 __attribute__((ext_vector_type(4)));
typedef const __attribute__((address_space(1))) float* gptr_t;
typedef __attribute__((address_space(3))) float* lptr_t;

constexpr int WAVES_PER_BLOCK = 4;   // 256 threads
constexpr int ROWS_PER_WAVE   = 4;   // rows per wave (per array)
constexpr int ROWS_PER_BLOCK  = WAVES_PER_BLOCK * ROWS_PER_WAVE;  // 16

__global__ __launch_bounds__(256) void cosine_rows_kernel(
    const float* __restrict__ q,   // [N, 256]
    const float* __restrict__ d,   // [N, 256]
    float* __restrict__ out,       // [N]
    int n_rows)
{
    // [wave][0=q,1=d][row][256 floats] = 4 * 8 KiB = 32 KiB
    __shared__ __align__(16) float smem[WAVES_PER_BLOCK][2][ROWS_PER_WAVE][256];

    const int tid  = threadIdx.x;
    const int w    = tid >> 6;
    const int lane = tid & 63;

    const int wave_row0 = blockIdx.x * ROWS_PER_BLOCK + w * ROWS_PER_WAVE;
    if (wave_row0 >= n_rows) return;   // never taken for N=262144; no barriers below

    // --- stage: 8 DMA instructions per wave, one full 1-KiB row each ---
    #pragma unroll
    for (int i = 0; i < ROWS_PER_WAVE; ++i) {
        const float* gq = q + (size_t)(wave_row0 + i) * 256 + lane * 4;
        __builtin_amdgcn_global_load_lds((gptr_t)gq, (lptr_t)&smem[w][0][i][0],
                                         16, 0, 0);
    }
    #pragma unroll
    for (int i = 0; i < ROWS_PER_WAVE; ++i) {
        const float* gd = d + (size_t)(wave_row0 + i) * 256 + lane * 4;
        __builtin_amdgcn_global_load_lds((gptr_t)gd, (lptr_t)&smem[w][1][i][0],
                                         16, 0, 0);
    }

    // Wave-private consumption: only this wave's DMAs must complete.
    asm volatile("s_waitcnt vmcnt(0)" ::: "memory");
    __builtin_amdgcn_sched_barrier(0);

    // --- reduce: 16 lanes per row, 4 rows per wave (R1 structure) ---
    const int g = lane >> 4;    // which of this wave's 4 rows
    const int c = lane & 15;    // chunk lane within the row

    const fx4* qrow = (const fx4*)&smem[w][0][g][0];
    const fx4* drow = (const fx4*)&smem[w][1][g][0];

    float qq = 0.0f, dd = 0.0f, qd = 0.0f;
    #pragma unroll
    for (int k = 0; k < 4; ++k) {
        const fx4 qv = qrow[c + 16 * k];
        const fx4 dv = drow[c + 16 * k];
        qq += qv.x * qv.x + qv.y * qv.y + qv.z * qv.z + qv.w * qv.w;
        dd += dv.x * dv.x + dv.y * dv.y + dv.z * dv.z + dv.w * dv.w;
        qd += qv.x * dv.x + qv.y * dv.y + qv.z * dv.z + qv.w * dv.w;
    }

    // 4-step butterfly within the 16-lane group.
    #pragma unroll
    for (int off = 8; off > 0; off >>= 1) {
        qq += __shfl_xor(qq, off, 64);
        dd += __shfl_xor(dd, off, 64);
        qd += __shfl_xor(qd, off, 64);
    }

    if (c == 0) {
        __builtin_nontemporal_store(qd * rsqrtf(qq * dd), &out[wave_row0 + g]);
    }
}

extern "C" void kernel_launch(void* const* d_in, const int* in_sizes, int n_in,
                              void* d_out, int out_size, void* d_ws, size_t ws_size,
                              hipStream_t stream) {
    const float* q = (const float*)d_in[0];
    const float* d = (const float*)d_in[1];
    float* out = (float*)d_out;

    const int D = 256;
    const int n_rows = in_sizes[0] / D;   // 262144, divisible by 16

    const int grid = (n_rows + ROWS_PER_BLOCK - 1) / ROWS_PER_BLOCK;  // 16384

    cosine_rows_kernel<<<grid, 256, 0, stream>>>(q, d, out, n_rows);
}